// Round 3
// baseline (140.846 us; speedup 1.0000x reference)
//
#include <hip/hip_runtime.h>
#include <hip/hip_bf16.h>
#include <hip/hip_fp8.h>

// Problem shape (fixed by setup_inputs)
#define SEQ   16384
#define DIN_  2048
#define DOUT_ 1024
#define NE_   8
#define TPE   (SEQ / NE_)   // 2048 tokens per expert
#define NG    (DIN_ / 128)  // 16 scale groups of K=128

typedef float f32x4 __attribute__((ext_vector_type(4)));
typedef int   i32x4 __attribute__((ext_vector_type(4)));
typedef int   i32x8 __attribute__((ext_vector_type(8)));

// async global->LDS, 16B per lane; LDS dest must be wave-uniform base + lane*16.
#define GLD(gp, lp) __builtin_amdgcn_global_load_lds( \
    (const __attribute__((address_space(1))) unsigned int*)(gp), \
    (__attribute__((address_space(3))) unsigned int*)(lp), 16, 0, 0)

// Exact reference rounding: clip(v/scale, +-448) -> e4m3fn (RNE, saturated)
__device__ __forceinline__ unsigned char fp8_byte(float v, float scale) {
    float r = v / scale;
    r = fminf(fmaxf(r, -448.0f), 448.0f);
    __hip_fp8_e4m3 q(r);
    return (unsigned char)q.__x;
}

// ---------------- activation quant: 1x128 tiles -> fp8 bytes + scale ----------------
// sxT layout: [16 groups][SEQ] f32 (transposed for contiguous GEMM staging)
__global__ __launch_bounds__(256) void quant_x_kernel(const float* __restrict__ X,
                                                      unsigned char* __restrict__ Xq,
                                                      float* __restrict__ sxT) {
    const int row  = blockIdx.x;
    const int t    = threadIdx.x;
    const int lane = t & 63;
    const int wave = t >> 6;
    const int tile = wave * 4 + (lane >> 4);   // 0..15 (group index)
    const int sub  = lane & 15;

    const float* p = X + (size_t)row * DIN_ + tile * 128 + sub * 8;
    float4 v0 = *(const float4*)p;
    float4 v1 = *(const float4*)(p + 4);

    float m = fmaxf(fmaxf(fmaxf(fabsf(v0.x), fabsf(v0.y)), fmaxf(fabsf(v0.z), fabsf(v0.w))),
                    fmaxf(fmaxf(fabsf(v1.x), fabsf(v1.y)), fmaxf(fabsf(v1.z), fabsf(v1.w))));
    #pragma unroll
    for (int off = 1; off < 16; off <<= 1)
        m = fmaxf(m, __shfl_xor(m, off, 64));

    const float scale = fmaxf(m, 1e-12f) / 448.0f;
    if (sub == 0) sxT[(size_t)tile * SEQ + row] = scale;

    unsigned lo = (unsigned)fp8_byte(v0.x, scale)
                | ((unsigned)fp8_byte(v0.y, scale) << 8)
                | ((unsigned)fp8_byte(v0.z, scale) << 16)
                | ((unsigned)fp8_byte(v0.w, scale) << 24);
    unsigned hi = (unsigned)fp8_byte(v1.x, scale)
                | ((unsigned)fp8_byte(v1.y, scale) << 8)
                | ((unsigned)fp8_byte(v1.z, scale) << 16)
                | ((unsigned)fp8_byte(v1.w, scale) << 24);
    uint2 u; u.x = lo; u.y = hi;
    *(uint2*)(Xq + (size_t)row * DIN_ + tile * 128 + sub * 8) = u;
}

// ---------------- weight quant: 128x128 blocks -> fp8 bytes + scale ----------------
// sw layout: [64 o-blocks][16 k-groups] f32
__global__ __launch_bounds__(256) void quant_w_kernel(const float* __restrict__ W,
                                                      unsigned char* __restrict__ Wq,
                                                      float* __restrict__ sw) {
    const int rb = blockIdx.x >> 4;    // o-block 0..63
    const int cb = blockIdx.x & 15;    // k-group 0..15
    const int t  = threadIdx.x;

    const float* base = W + (size_t)(rb * 128) * DIN_ + cb * 128;
    const int r0 = t >> 5;
    const int c0 = (t & 31) * 4;

    float4 v[16];
    float m = 0.0f;
    #pragma unroll
    for (int i = 0; i < 16; ++i) {
        v[i] = *(const float4*)(base + (size_t)(i * 8 + r0) * DIN_ + c0);
        m = fmaxf(m, fmaxf(fmaxf(fabsf(v[i].x), fabsf(v[i].y)),
                           fmaxf(fabsf(v[i].z), fabsf(v[i].w))));
    }
    #pragma unroll
    for (int off = 1; off < 64; off <<= 1)
        m = fmaxf(m, __shfl_xor(m, off, 64));
    __shared__ float smx[4];
    if ((t & 63) == 0) smx[t >> 6] = m;
    __syncthreads();
    const float amax  = fmaxf(fmaxf(smx[0], smx[1]), fmaxf(smx[2], smx[3]));
    const float scale = fmaxf(amax, 1e-12f) / 448.0f;
    if (t == 0) sw[rb * 16 + cb] = scale;

    unsigned char* obase = Wq + (size_t)(rb * 128) * DIN_ + cb * 128;
    #pragma unroll
    for (int i = 0; i < 16; ++i) {
        unsigned u = (unsigned)fp8_byte(v[i].x, scale)
                   | ((unsigned)fp8_byte(v[i].y, scale) << 8)
                   | ((unsigned)fp8_byte(v[i].z, scale) << 16)
                   | ((unsigned)fp8_byte(v[i].w, scale) << 24);
        *(unsigned int*)(obase + (size_t)(i * 8 + r0) * DIN_ + c0) = u;
    }
}

// ---------------- grouped GEMM: fp8 data, mfma_scale 16x16x128 (unit e8m0 scales) ---
// 256x256 tile, 8 waves (2M x 4N), per-wave 128x64 out = acc[8][4].
// Per K-group g (K=128): partial = mfma(qa,qb,0); acc += partial * sx[row,g]*sw[oblk,g].
// LDS: A[2][256][128]B @0, B[2][256][128]B @65536, sxT tile [16][256]f32 @131072 (144KB).
// Swizzle: byte p ^= ((row&7)<<4); staged via pre-swizzled global source (linear dest).
// Pipeline: stage group g+2 after phase-B read-complete barrier; gates vmcnt(8)/(0).
__global__ __launch_bounds__(512, 2) void gemm_kernel(const unsigned char* __restrict__ Xq,
                                                      const unsigned char* __restrict__ Wq,
                                                      const float* __restrict__ sxT,
                                                      const float* __restrict__ sw,
                                                      float* __restrict__ out) {
    __shared__ unsigned char lds[147456];

    // T1: bijective XCD swizzle; 256 blocks = 8 XCDs x 32 (one expert per XCD)
    const int bid  = blockIdx.x;
    const int wgid = (bid & 7) * 32 + (bid >> 3);
    const int e    = wgid >> 5;
    const int tile = wgid & 31;
    const int brow = tile >> 2;   // 0..7
    const int bcol = tile & 3;    // 0..3

    const int t    = threadIdx.x;
    const int lane = t & 63;
    const int wave = t >> 6;
    const int wm   = wave >> 2;   // 0..1
    const int wn   = wave & 3;    // 0..3

    const int row0 = e * TPE + brow * 256;
    const unsigned char* Xt = Xq + (size_t)row0 * DIN_;
    const unsigned char* Wt = Wq + (size_t)(e * DOUT_ + bcol * 256) * DIN_;
    const float* swp = sw + (size_t)(e * 8 + bcol * 2 + (wn >> 1)) * 16;

    // stage one full K-group (A 32KB + B 32KB): 8 GLD16/thread, swizzled source
    auto stage_group = [&](int g) {
        if (g >= NG) return;
        const unsigned abase = (unsigned)(g & 1) * 32768u;
        #pragma unroll
        for (int i = 0; i < 4; ++i) {
            const unsigned p = (unsigned)i * 8192u + (unsigned)t * 16u;
            const unsigned q = p ^ (((p >> 7) & 7u) << 4);
            GLD(Xt + (size_t)(q >> 7) * DIN_ + g * 128 + (q & 127u), &lds[abase + p]);
        }
        #pragma unroll
        for (int i = 0; i < 4; ++i) {
            const unsigned p = (unsigned)i * 8192u + (unsigned)t * 16u;
            const unsigned q = p ^ (((p >> 7) & 7u) << 4);
            GLD(Wt + (size_t)(q >> 7) * DIN_ + g * 128 + (q & 127u), &lds[65536u + abase + p]);
        }
    };

    // fragment read: logical (row r, k-chunk kc) -> 32B (two swizzled b128)
    auto ld_frag = [&](unsigned base, unsigned r) -> i32x8 {
        const unsigned kc  = (unsigned)(lane >> 4);
        const unsigned msk = (r & 7u) << 4;
        const unsigned p0  = (r * 128u + kc * 32u) ^ msk;
        const unsigned p1  = (r * 128u + kc * 32u + 16u) ^ msk;
        i32x4 lo = *(const i32x4*)&lds[base + p0];
        i32x4 hi = *(const i32x4*)&lds[base + p1];
        return __builtin_shufflevector(lo, hi, 0, 1, 2, 3, 4, 5, 6, 7);
    };
    // per-(m-frag, group) row scales: 4 consecutive rows for this lane
    auto ld_sx = [&](int m, int g) -> f32x4 {
        const unsigned r = (unsigned)(wm * 128 + m * 16 + ((lane >> 4) << 2));
        return *(const f32x4*)&lds[131072u + (unsigned)g * 1024u + r * 4u];
    };

    f32x4 acc[8][4] = {};
    const f32x4 zero = {0.f, 0.f, 0.f, 0.f};

    // prologue: sx tile (2 GLD) + groups 0,1 (16 GLD); wait until sx+g0 landed
    #pragma unroll
    for (int i = 0; i < 2; ++i) {
        const unsigned p = (unsigned)i * 8192u + (unsigned)t * 16u;  // 16KB
        GLD((const unsigned char*)sxT + ((size_t)(p >> 10) * SEQ + row0) * 4 + (p & 1023u),
            &lds[131072u + p]);
    }
    stage_group(0);
    stage_group(1);
    asm volatile("s_waitcnt vmcnt(8)" ::: "memory");
    __builtin_amdgcn_s_barrier();

    for (int g = 0; g < NG; ++g) {
        const unsigned abase = (unsigned)(g & 1) * 32768u;
        const unsigned bbase = 65536u + abase;
        const float swg = __uint_as_float(
            __builtin_amdgcn_readfirstlane(__float_as_uint(swp[g])));

        i32x8 bfr[4];
        #pragma unroll
        for (int n = 0; n < 4; ++n)
            bfr[n] = ld_frag(bbase, (unsigned)(wn * 64 + n * 16 + (lane & 15)));

        // ---- phase A: m-frags 0-3 ----
        {
            i32x8 afr[4]; f32x4 sxv[4];
            #pragma unroll
            for (int m = 0; m < 4; ++m) {
                afr[m] = ld_frag(abase, (unsigned)(wm * 128 + m * 16 + (lane & 15)));
                sxv[m] = ld_sx(m, g);
            }
            asm volatile("s_waitcnt lgkmcnt(0)" ::: "memory");
            __builtin_amdgcn_sched_barrier(0);
            __builtin_amdgcn_s_setprio(1);
            #pragma unroll
            for (int m = 0; m < 4; ++m) {
                const f32x4 sf = sxv[m] * swg;
                #pragma unroll
                for (int n = 0; n < 4; ++n) {
                    f32x4 pn = __builtin_amdgcn_mfma_scale_f32_16x16x128_f8f6f4(
                        afr[m], bfr[n], zero, 0, 0, 0, 0x7f7f7f7f, 0, 0x7f7f7f7f);
                    acc[m][n] += pn * sf;
                }
            }
            __builtin_amdgcn_s_setprio(0);
        }

        // ---- phase B: m-frags 4-7; then overwrite buf with group g+2 ----
        {
            i32x8 afr[4]; f32x4 sxv[4];
            #pragma unroll
            for (int m = 0; m < 4; ++m) {
                afr[m] = ld_frag(abase, (unsigned)(wm * 128 + (m + 4) * 16 + (lane & 15)));
                sxv[m] = ld_sx(m + 4, g);
            }
            asm volatile("s_waitcnt lgkmcnt(0)" ::: "memory");
            __builtin_amdgcn_sched_barrier(0);
            __builtin_amdgcn_s_barrier();   // all waves done READING this buf
            stage_group(g + 2);             // async overwrite (consumed at g+2's gate)
            __builtin_amdgcn_s_setprio(1);
            #pragma unroll
            for (int m = 0; m < 4; ++m) {
                const f32x4 sf = sxv[m] * swg;
                #pragma unroll
                for (int n = 0; n < 4; ++n) {
                    f32x4 pn = __builtin_amdgcn_mfma_scale_f32_16x16x128_f8f6f4(
                        afr[m], bfr[n], zero, 0, 0, 0, 0x7f7f7f7f, 0, 0x7f7f7f7f);
                    acc[m + 4][n] += pn * sf;
                }
            }
            __builtin_amdgcn_s_setprio(0);
        }

        // gate: group g+1 must be landed before next iteration reads it
        if (g < NG - 1) {
            if (g <= NG - 3)
                asm volatile("s_waitcnt vmcnt(8)" ::: "memory");  // 8 newest = g+2's
            else
                asm volatile("s_waitcnt vmcnt(0)" ::: "memory");  // no g+2 staged
            __builtin_amdgcn_s_barrier();
        }
    }

    // epilogue: C/D mapping col = lane&15, row = (lane>>4)*4 + j
    const int orow0 = e * TPE + brow * 256 + wm * 128;
    const int ocol0 = bcol * 256 + wn * 64;
    const int rl = (lane >> 4) * 4;
    const int cl = lane & 15;
    #pragma unroll
    for (int m = 0; m < 8; ++m)
        #pragma unroll
        for (int n = 0; n < 4; ++n)
            #pragma unroll
            for (int j = 0; j < 4; ++j) {
                const int r = orow0 + m * 16 + rl + j;
                const int c = ocol0 + n * 16 + cl;
                out[(size_t)r * DOUT_ + c] = acc[m][n][j];
            }
}

extern "C" void kernel_launch(void* const* d_in, const int* in_sizes, int n_in,
                              void* d_out, int out_size, void* d_ws, size_t ws_size,
                              hipStream_t stream) {
    const float* x = (const float*)d_in[0];
    // d_in[1] = tokens_per_expert: reference assumes equal split, unused.
    const float* w = (const float*)d_in[2];
    float* out = (float*)d_out;

    // workspace: xq 32MiB | wq 16MiB | sxT 1MiB | sw 4KiB
    unsigned char* xq = (unsigned char*)d_ws;
    unsigned char* wq = xq + (size_t)SEQ * DIN_;
    float* sxT = (float*)(wq + (size_t)NE_ * DOUT_ * DIN_);
    float* sw  = sxT + (size_t)NG * SEQ;

    quant_x_kernel<<<SEQ, 256, 0, stream>>>(x, xq, sxT);
    quant_w_kernel<<<(NE_ * DOUT_ / 128) * (DIN_ / 128), 256, 0, stream>>>(w, wq, sw);
    gemm_kernel<<<NE_ * (TPE / 256) * (DOUT_ / 256), 512, 0, stream>>>(xq, wq, sxT, sw, out);
}

// Round 4
// 125.027 us; speedup vs baseline: 1.1265x; 1.1265x over previous
//
#include <hip/hip_runtime.h>
#include <hip/hip_bf16.h>
#include <hip/hip_fp8.h>

// Problem shape (fixed by setup_inputs)
#define SEQ   16384
#define DIN_  2048
#define DOUT_ 1024
#define NE_   8
#define TPE   (SEQ / NE_)   // 2048 tokens per expert
#define NT    (DIN_ / 64)   // 32 K-tiles of 64

typedef __bf16 bf16x8 __attribute__((ext_vector_type(8)));
typedef __bf16 bf16x4 __attribute__((ext_vector_type(4)));
typedef float  f32x4  __attribute__((ext_vector_type(4)));

// async global->LDS, 16B per lane. LDS dest must be wave-linear (base + lane*16).
#define GLD(gp, lp) __builtin_amdgcn_global_load_lds( \
    (const __attribute__((address_space(1))) unsigned int*)(gp), \
    (__attribute__((address_space(3))) unsigned int*)(lp), 16, 0, 0)

// Reference fp8_round with the tile-wide divide hoisted: r = v*(1/scale)
// (≤1-ulp fp8 difference on rounding-boundary ties only; dequant mul by s is exact.)
__device__ __forceinline__ float fp8_round_dq_m(float v, float sinv, float s) {
    float r = v * sinv;
    r = fminf(fmaxf(r, -448.0f), 448.0f);
    __hip_fp8_e4m3 q(r);   // OCP e4m3fn, RNE, saturated
    return (float)q * s;
}

// ---------------- fused quant-dequant (activations + weights) ----------------
// blocks [0, SEQ): one X row each (16 tiles of 1x128)
// blocks [SEQ, SEQ+1024): one 128x128 W block each
__global__ __launch_bounds__(256) void quant_kernel(const float* __restrict__ X,
                                                    const float* __restrict__ W,
                                                    __bf16* __restrict__ Xq,
                                                    __bf16* __restrict__ Wq) {
    const int t = threadIdx.x;
    if (blockIdx.x < SEQ) {
        // ----- activation row -----
        const int row  = blockIdx.x;
        const int lane = t & 63;
        const int wave = t >> 6;
        const int tile = wave * 4 + (lane >> 4);   // 0..15
        const int sub  = lane & 15;

        const float* p = X + (size_t)row * DIN_ + tile * 128 + sub * 8;
        float4 v0 = *(const float4*)p;
        float4 v1 = *(const float4*)(p + 4);

        float m = fmaxf(fmaxf(fmaxf(fabsf(v0.x), fabsf(v0.y)), fmaxf(fabsf(v0.z), fabsf(v0.w))),
                        fmaxf(fmaxf(fabsf(v1.x), fabsf(v1.y)), fmaxf(fabsf(v1.z), fabsf(v1.w))));
        #pragma unroll
        for (int off = 1; off < 16; off <<= 1)
            m = fmaxf(m, __shfl_xor(m, off, 64));

        const float s    = fmaxf(m, 1e-12f) / 448.0f;
        const float sinv = 1.0f / s;

        bf16x8 o;
        o[0] = (__bf16)fp8_round_dq_m(v0.x, sinv, s);
        o[1] = (__bf16)fp8_round_dq_m(v0.y, sinv, s);
        o[2] = (__bf16)fp8_round_dq_m(v0.z, sinv, s);
        o[3] = (__bf16)fp8_round_dq_m(v0.w, sinv, s);
        o[4] = (__bf16)fp8_round_dq_m(v1.x, sinv, s);
        o[5] = (__bf16)fp8_round_dq_m(v1.y, sinv, s);
        o[6] = (__bf16)fp8_round_dq_m(v1.z, sinv, s);
        o[7] = (__bf16)fp8_round_dq_m(v1.w, sinv, s);
        *(bf16x8*)(Xq + (size_t)row * DIN_ + tile * 128 + sub * 8) = o;
    } else {
        // ----- weight 128x128 block -----
        const int b  = blockIdx.x - SEQ;
        const int rb = b >> 4;
        const int cb = b & 15;

        const float* base = W + (size_t)(rb * 128) * DIN_ + cb * 128;
        const int r0 = t >> 5;
        const int c0 = (t & 31) * 4;

        float4 v[16];
        float m = 0.0f;
        #pragma unroll
        for (int i = 0; i < 16; ++i) {
            v[i] = *(const float4*)(base + (size_t)(i * 8 + r0) * DIN_ + c0);
            m = fmaxf(m, fmaxf(fmaxf(fabsf(v[i].x), fabsf(v[i].y)),
                               fmaxf(fabsf(v[i].z), fabsf(v[i].w))));
        }
        #pragma unroll
        for (int off = 1; off < 64; off <<= 1)
            m = fmaxf(m, __shfl_xor(m, off, 64));
        __shared__ float smx[4];
        if ((t & 63) == 0) smx[t >> 6] = m;
        __syncthreads();
        const float amax = fmaxf(fmaxf(smx[0], smx[1]), fmaxf(smx[2], smx[3]));
        const float s    = fmaxf(amax, 1e-12f) / 448.0f;
        const float sinv = 1.0f / s;

        __bf16* obase = Wq + (size_t)(rb * 128) * DIN_ + cb * 128;
        #pragma unroll
        for (int i = 0; i < 16; ++i) {
            bf16x4 o;
            o[0] = (__bf16)fp8_round_dq_m(v[i].x, sinv, s);
            o[1] = (__bf16)fp8_round_dq_m(v[i].y, sinv, s);
            o[2] = (__bf16)fp8_round_dq_m(v[i].z, sinv, s);
            o[3] = (__bf16)fp8_round_dq_m(v[i].w, sinv, s);
            *(bf16x4*)(obase + (size_t)(i * 8 + r0) * DIN_ + c0) = o;
        }
    }
}

// ---------------- grouped GEMM: 256x256 tile, BK=64, 8-phase pipelined ----------------
// out[e*TPE + t, o] = sum_d Xq[e*TPE + t, d] * Wq[e*DOUT + o, d]
// 8 waves (2M x 4N), per-wave 128x64 out = acc[8][4] f32x4.
// LDS 128 KiB = 8 half-regions of [256 rows][32 k] bf16 (16 KiB each).
// Half-tile sequence per K-tile kt: H=4kt+{0:B-kh0, 1:A-kh0, 2:B-kh1, 3:A-kh1}.
// vmcnt(6) per K-tile boundary (3 half-tiles in flight).
// Swizzle (T2): byte p ^= ((p>>7)&3)<<4 within each region.
__global__ __launch_bounds__(512, 2) void gemm_kernel(const __bf16* __restrict__ X,
                                                      const __bf16* __restrict__ W,
                                                      float* __restrict__ out) {
    __shared__ __bf16 lds[65536];   // 128 KiB

    // T1: bijective XCD swizzle; 256 blocks = 8 XCDs x 32 tiles = 1 expert/XCD
    const int bid  = blockIdx.x;
    const int wgid = (bid & 7) * 32 + (bid >> 3);
    const int e    = wgid >> 5;
    const int tile = wgid & 31;
    const int brow = tile >> 2;   // 0..7
    const int bcol = tile & 3;    // 0..3

    const int t     = threadIdx.x;
    const int lane  = t & 63;
    const int wave  = t >> 6;
    const int wm    = wave >> 2;  // 0..1
    const int wn    = wave & 3;   // 0..3
    const int flane = lane & 15;

    const __bf16* Xt = X + (size_t)(e * TPE + brow * 256) * DIN_;
    const __bf16* Wt = W + (size_t)(e * DOUT_ + bcol * 256) * DIN_;

    auto stage_half = [&](int H) {
        if (H >= 4 * NT) return;
        const int kt2  = H >> 2;
        const int typ  = H & 3;          // 0:B-kh0 1:A-kh0 2:B-kh1 3:A-kh1
        const int kh   = typ >> 1;
        const bool isA = (typ & 1) != 0;
        const int buf  = kt2 & 1;
        const __bf16* src = isA ? Xt : Wt;
        const unsigned rbase = (isA ? 0u : 32768u) + (unsigned)(buf * 2 + kh) * 8192u;
        #pragma unroll
        for (int i = 0; i < 2; ++i) {
            const unsigned p = (unsigned)i * 8192u + (unsigned)t * 16u;  // byte off in region
            const unsigned q = p ^ (((p >> 7) & 3u) << 4);               // involution
            const unsigned srow = q >> 6;
            const unsigned scol = (q & 63u) >> 1;
            GLD(src + (size_t)srow * DIN_ + kt2 * 64 + kh * 32 + scol,
                &lds[rbase + p / 2]);
        }
    };

    auto ld_frag = [&](unsigned rbase, int row) -> bf16x8 {
        unsigned p = (unsigned)row * 64u + (unsigned)(lane >> 4) * 16u;
        p ^= ((p >> 7) & 3u) << 4;
        return *(const bf16x8*)&lds[rbase + p / 2];
    };

    f32x4 acc[8][4] = {};

    stage_half(0); stage_half(1); stage_half(2); stage_half(3);
    stage_half(4); stage_half(5); stage_half(6);
    asm volatile("s_waitcnt vmcnt(6)" ::: "memory");
    __builtin_amdgcn_s_barrier();

    for (int kt = 0; kt < NT; ++kt) {
        const int buf = kt & 1;
        const unsigned A0 = (unsigned)(buf * 2 + 0) * 8192u;
        const unsigned A1 = (unsigned)(buf * 2 + 1) * 8192u;
        const unsigned B0 = 32768u + (unsigned)(buf * 2 + 0) * 8192u;
        const unsigned B1 = 32768u + (unsigned)(buf * 2 + 1) * 8192u;
        const int H0 = 4 * kt + 7;

        bf16x8 a[4], b[4];

        // ---- phase 1: kh0, m-frags 0-3 ----
        #pragma unroll
        for (int n = 0; n < 4; ++n) b[n] = ld_frag(B0, wn * 64 + n * 16 + flane);
        #pragma unroll
        for (int m = 0; m < 4; ++m) a[m] = ld_frag(A0, wm * 128 + m * 16 + flane);
        stage_half(H0);
        __builtin_amdgcn_s_barrier();
        asm volatile("s_waitcnt lgkmcnt(0)" ::: "memory");
        __builtin_amdgcn_sched_barrier(0);
        __builtin_amdgcn_s_setprio(1);
        #pragma unroll
        for (int m = 0; m < 4; ++m)
            #pragma unroll
            for (int n = 0; n < 4; ++n)
                acc[m][n] = __builtin_amdgcn_mfma_f32_16x16x32_bf16(a[m], b[n], acc[m][n], 0, 0, 0);
        __builtin_amdgcn_s_setprio(0);
        __builtin_amdgcn_s_barrier();

        // ---- phase 2: kh0, m-frags 4-7 (B regs reused) ----
        #pragma unroll
        for (int m = 0; m < 4; ++m) a[m] = ld_frag(A0, wm * 128 + (m + 4) * 16 + flane);
        stage_half(H0 + 1);
        __builtin_amdgcn_s_barrier();
        asm volatile("s_waitcnt lgkmcnt(0)" ::: "memory");
        __builtin_amdgcn_sched_barrier(0);
        __builtin_amdgcn_s_setprio(1);
        #pragma unroll
        for (int m = 0; m < 4; ++m)
            #pragma unroll
            for (int n = 0; n < 4; ++n)
                acc[m + 4][n] = __builtin_amdgcn_mfma_f32_16x16x32_bf16(a[m], b[n], acc[m + 4][n], 0, 0, 0);
        __builtin_amdgcn_s_setprio(0);
        __builtin_amdgcn_s_barrier();

        // ---- phase 3: kh1, m-frags 0-3 ----
        #pragma unroll
        for (int n = 0; n < 4; ++n) b[n] = ld_frag(B1, wn * 64 + n * 16 + flane);
        #pragma unroll
        for (int m = 0; m < 4; ++m) a[m] = ld_frag(A1, wm * 128 + m * 16 + flane);
        stage_half(H0 + 2);
        __builtin_amdgcn_s_barrier();
        asm volatile("s_waitcnt lgkmcnt(0)" ::: "memory");
        __builtin_amdgcn_sched_barrier(0);
        __builtin_amdgcn_s_setprio(1);
        #pragma unroll
        for (int m = 0; m < 4; ++m)
            #pragma unroll
            for (int n = 0; n < 4; ++n)
                acc[m][n] = __builtin_amdgcn_mfma_f32_16x16x32_bf16(a[m], b[n], acc[m][n], 0, 0, 0);
        __builtin_amdgcn_s_setprio(0);
        __builtin_amdgcn_s_barrier();

        // ---- phase 4: kh1, m-frags 4-7 ----
        #pragma unroll
        for (int m = 0; m < 4; ++m) a[m] = ld_frag(A1, wm * 128 + (m + 4) * 16 + flane);
        stage_half(H0 + 3);
        __builtin_amdgcn_s_barrier();
        asm volatile("s_waitcnt lgkmcnt(0)" ::: "memory");
        __builtin_amdgcn_sched_barrier(0);
        __builtin_amdgcn_s_setprio(1);
        #pragma unroll
        for (int m = 0; m < 4; ++m)
            #pragma unroll
            for (int n = 0; n < 4; ++n)
                acc[m + 4][n] = __builtin_amdgcn_mfma_f32_16x16x32_bf16(a[m], b[n], acc[m + 4][n], 0, 0, 0);
        __builtin_amdgcn_s_setprio(0);
        if (kt < NT - 2) {
            asm volatile("s_waitcnt vmcnt(6)" ::: "memory");
        } else {
            asm volatile("s_waitcnt vmcnt(0)" ::: "memory");
        }
        __builtin_amdgcn_s_barrier();
    }

    // epilogue: C/D mapping col = lane&15, row = (lane>>4)*4 + j
    const int orow0 = e * TPE + brow * 256 + wm * 128;
    const int ocol0 = bcol * 256 + wn * 64;
    const int rl = (lane >> 4) * 4;
    const int cl = lane & 15;
    #pragma unroll
    for (int m = 0; m < 8; ++m)
        #pragma unroll
        for (int n = 0; n < 4; ++n)
            #pragma unroll
            for (int j = 0; j < 4; ++j) {
                const int r = orow0 + m * 16 + rl + j;
                const int c = ocol0 + n * 16 + cl;
                out[(size_t)r * DOUT_ + c] = acc[m][n][j];
            }
}

extern "C" void kernel_launch(void* const* d_in, const int* in_sizes, int n_in,
                              void* d_out, int out_size, void* d_ws, size_t ws_size,
                              hipStream_t stream) {
    const float* x = (const float*)d_in[0];
    // d_in[1] = tokens_per_expert: reference assumes equal split, unused.
    const float* w = (const float*)d_in[2];
    float* out = (float*)d_out;

    // workspace: xq bf16 (64 MiB) + wq bf16 (32 MiB)
    __bf16* xq = (__bf16*)d_ws;
    __bf16* wq = (__bf16*)((char*)d_ws + (size_t)SEQ * DIN_ * sizeof(__bf16));

    quant_kernel<<<SEQ + (NE_ * DOUT_ / 128) * (DIN_ / 128), 256, 0, stream>>>(x, w, xq, wq);
    gemm_kernel<<<NE_ * (TPE / 256) * (DOUT_ / 256), 512, 0, stream>>>(xq, wq, out);
}

// Round 5
// 121.099 us; speedup vs baseline: 1.1631x; 1.0324x over previous
//
#include <hip/hip_runtime.h>
#include <hip/hip_bf16.h>
#include <hip/hip_fp8.h>

// Problem shape (fixed by setup_inputs)
#define SEQ   16384
#define DIN_  2048
#define DOUT_ 1024
#define NE_   8
#define TPE   (SEQ / NE_)   // 2048 tokens per expert
#define NT    (DIN_ / 64)   // 32 K-tiles of 64

typedef __bf16 bf16x8 __attribute__((ext_vector_type(8)));
typedef __bf16 bf16x4 __attribute__((ext_vector_type(4)));
typedef float  f32x4  __attribute__((ext_vector_type(4)));

// async global->LDS, 16B per lane. LDS dest must be wave-linear (base + lane*16).
#define GLD(gp, lp) __builtin_amdgcn_global_load_lds( \
    (const __attribute__((address_space(1))) unsigned int*)(gp), \
    (__attribute__((address_space(3))) unsigned int*)(lp), 16, 0, 0)

// Reference fp8_round with the tile-wide divide hoisted: r = v*(1/scale)
__device__ __forceinline__ float fp8_round_dq_m(float v, float sinv, float s) {
    float r = v * sinv;
    r = fminf(fmaxf(r, -448.0f), 448.0f);
    __hip_fp8_e4m3 q(r);   // OCP e4m3fn, RNE, saturated
    return (float)q * s;
}

// ---------------- activation quant-dequant: 1x128 tiles, 2 rows per block ----------------
__global__ __launch_bounds__(256) void quant_x_kernel(const float* __restrict__ X,
                                                      __bf16* __restrict__ Xq) {
    const int t    = threadIdx.x;
    const int lane = t & 63;
    const int wave = t >> 6;
    const int tile = wave * 4 + (lane >> 4);   // 0..15
    const int sub  = lane & 15;
    const size_t off = (size_t)tile * 128 + sub * 8;

    const int row0 = blockIdx.x * 2;
    const float* pa = X + (size_t)row0 * DIN_ + off;
    const float* pb = X + (size_t)(row0 + 1) * DIN_ + off;

    float4 a0 = *(const float4*)pa;
    float4 a1 = *(const float4*)(pa + 4);
    float4 b0 = *(const float4*)pb;
    float4 b1 = *(const float4*)(pb + 4);

    float ma = fmaxf(fmaxf(fmaxf(fabsf(a0.x), fabsf(a0.y)), fmaxf(fabsf(a0.z), fabsf(a0.w))),
                     fmaxf(fmaxf(fabsf(a1.x), fabsf(a1.y)), fmaxf(fabsf(a1.z), fabsf(a1.w))));
    float mb = fmaxf(fmaxf(fmaxf(fabsf(b0.x), fabsf(b0.y)), fmaxf(fabsf(b0.z), fabsf(b0.w))),
                     fmaxf(fmaxf(fabsf(b1.x), fabsf(b1.y)), fmaxf(fabsf(b1.z), fabsf(b1.w))));
    #pragma unroll
    for (int off2 = 1; off2 < 16; off2 <<= 1) {
        ma = fmaxf(ma, __shfl_xor(ma, off2, 64));
        mb = fmaxf(mb, __shfl_xor(mb, off2, 64));
    }

    const float sa = fmaxf(ma, 1e-12f) / 448.0f, sia = 1.0f / sa;
    const float sb = fmaxf(mb, 1e-12f) / 448.0f, sib = 1.0f / sb;

    bf16x8 oa, ob;
    oa[0] = (__bf16)fp8_round_dq_m(a0.x, sia, sa);
    oa[1] = (__bf16)fp8_round_dq_m(a0.y, sia, sa);
    oa[2] = (__bf16)fp8_round_dq_m(a0.z, sia, sa);
    oa[3] = (__bf16)fp8_round_dq_m(a0.w, sia, sa);
    oa[4] = (__bf16)fp8_round_dq_m(a1.x, sia, sa);
    oa[5] = (__bf16)fp8_round_dq_m(a1.y, sia, sa);
    oa[6] = (__bf16)fp8_round_dq_m(a1.z, sia, sa);
    oa[7] = (__bf16)fp8_round_dq_m(a1.w, sia, sa);
    ob[0] = (__bf16)fp8_round_dq_m(b0.x, sib, sb);
    ob[1] = (__bf16)fp8_round_dq_m(b0.y, sib, sb);
    ob[2] = (__bf16)fp8_round_dq_m(b0.z, sib, sb);
    ob[3] = (__bf16)fp8_round_dq_m(b0.w, sib, sb);
    ob[4] = (__bf16)fp8_round_dq_m(b1.x, sib, sb);
    ob[5] = (__bf16)fp8_round_dq_m(b1.y, sib, sb);
    ob[6] = (__bf16)fp8_round_dq_m(b1.z, sib, sb);
    ob[7] = (__bf16)fp8_round_dq_m(b1.w, sib, sb);
    *(bf16x8*)(Xq + (size_t)row0 * DIN_ + off) = oa;
    *(bf16x8*)(Xq + (size_t)(row0 + 1) * DIN_ + off) = ob;
}

// ---------------- weight quant-dequant: 128x128 blocks (own kernel, no spill) ----------
__global__ __launch_bounds__(256) void quant_w_kernel(const float* __restrict__ W,
                                                      __bf16* __restrict__ Wq) {
    const int rb = blockIdx.x >> 4;
    const int cb = blockIdx.x & 15;
    const int t  = threadIdx.x;

    const float* base = W + (size_t)(rb * 128) * DIN_ + cb * 128;
    const int r0 = t >> 5;
    const int c0 = (t & 31) * 4;

    float4 v[16];
    float m = 0.0f;
    #pragma unroll
    for (int i = 0; i < 16; ++i) {
        v[i] = *(const float4*)(base + (size_t)(i * 8 + r0) * DIN_ + c0);
        m = fmaxf(m, fmaxf(fmaxf(fabsf(v[i].x), fabsf(v[i].y)),
                           fmaxf(fabsf(v[i].z), fabsf(v[i].w))));
    }
    #pragma unroll
    for (int off = 1; off < 64; off <<= 1)
        m = fmaxf(m, __shfl_xor(m, off, 64));
    __shared__ float smx[4];
    if ((t & 63) == 0) smx[t >> 6] = m;
    __syncthreads();
    const float amax = fmaxf(fmaxf(smx[0], smx[1]), fmaxf(smx[2], smx[3]));
    const float s    = fmaxf(amax, 1e-12f) / 448.0f;
    const float sinv = 1.0f / s;

    __bf16* obase = Wq + (size_t)(rb * 128) * DIN_ + cb * 128;
    #pragma unroll
    for (int i = 0; i < 16; ++i) {
        bf16x4 o;
        o[0] = (__bf16)fp8_round_dq_m(v[i].x, sinv, s);
        o[1] = (__bf16)fp8_round_dq_m(v[i].y, sinv, s);
        o[2] = (__bf16)fp8_round_dq_m(v[i].z, sinv, s);
        o[3] = (__bf16)fp8_round_dq_m(v[i].w, sinv, s);
        *(bf16x4*)(obase + (size_t)(i * 8 + r0) * DIN_ + c0) = o;
    }
}

// ---------------- grouped GEMM: 256x256 tile, BK=64, 8-phase, full-width LDS rows -----
// LDS 128 KiB: A regions [256 rows][128 B] at {0, 32768}; B at {65536, 98304}.
// Rows are full BK=64 wide -> staging GLDs fetch consecutive 128B lines (8 lanes/row).
// Swizzle: byte p ^= ((p>>7)&7)<<4 (permutes 16B slots within a row; 2-way banks).
// Part map per tile k: H=4k+{0:B-lo, 1:B-hi, 2:A-lo, 3:A-hi}; issue slot of part r of
// tile kt+2 = {r0: ph2, r1: ph3, r2: ph4, r3: next ph1} -- every overwrite is
// barrier-separated from (or program-order-after) its region's last reader.
// Phase order: {kh0 m0-3, kh1 m0-3, kh0 m4-7, kh1 m4-7}; b0/b1 frags held in regs.
__global__ __launch_bounds__(512, 2) void gemm_kernel(const __bf16* __restrict__ X,
                                                      const __bf16* __restrict__ W,
                                                      float* __restrict__ out) {
    __shared__ __align__(16) unsigned char lds[131072];

    // T1: bijective XCD swizzle; 256 blocks = 8 XCDs x 32 (one expert per XCD)
    const int bid  = blockIdx.x;
    const int wgid = (bid & 7) * 32 + (bid >> 3);
    const int e    = wgid >> 5;
    const int tile = wgid & 31;
    const int brow = tile >> 2;   // 0..7
    const int bcol = tile & 3;    // 0..3

    const int t     = threadIdx.x;
    const int lane  = t & 63;
    const int wave  = t >> 6;
    const int wm    = wave >> 2;  // 0..1
    const int wn    = wave & 3;   // 0..3
    const int flane = lane & 15;

    const __bf16* Xt = X + (size_t)(e * TPE + brow * 256) * DIN_;
    const __bf16* Wt = W + (size_t)(e * DOUT_ + bcol * 256) * DIN_;

    auto stage_part = [&](int H) {
        if (H >= 4 * NT) return;
        const int k2   = H >> 2;
        const int r    = H & 3;          // 0:B-lo 1:B-hi 2:A-lo 3:A-hi
        const bool isB = (r < 2);
        const int half = r & 1;
        const int buf  = k2 & 1;
        const __bf16* src = isB ? Wt : Xt;
        const unsigned base = (isB ? 65536u : 0u) + (unsigned)buf * 32768u
                            + (unsigned)half * 16384u;
        #pragma unroll
        for (int i = 0; i < 2; ++i) {
            const unsigned p = (unsigned)i * 8192u + (unsigned)t * 16u;
            const unsigned q = p ^ (((p >> 7) & 7u) << 4);   // involution, within-row
            GLD(src + (size_t)(half * 128 + (q >> 7)) * DIN_ + k2 * 64 + ((q & 127u) >> 1),
                &lds[base + p]);
        }
    };

    auto ld_frag = [&](unsigned base, int row, int kh) -> bf16x8 {
        unsigned p = (unsigned)row * 128u + (unsigned)kh * 64u + (unsigned)(lane >> 4) * 16u;
        p ^= ((p >> 7) & 7u) << 4;
        return *(const bf16x8*)&lds[base + p];
    };

    f32x4 acc[8][4] = {};

    // prologue: tile0 all 4 parts + tile1 {B-lo,B-hi,A-lo}; wait tile0 landed
    stage_part(0); stage_part(1); stage_part(2); stage_part(3);
    stage_part(4); stage_part(5); stage_part(6);
    asm volatile("s_waitcnt vmcnt(6)" ::: "memory");
    __builtin_amdgcn_s_barrier();

    for (int kt = 0; kt < NT; ++kt) {
        const int buf = kt & 1;
        const unsigned Ab = (unsigned)buf * 32768u;
        const unsigned Bb = 65536u + (unsigned)buf * 32768u;
        const int H0 = 4 * kt + 7;

        bf16x8 b0[4], b1[4], a[4];

        // ---- phase 1: kh0, m0-3 (reads b0 + a) ----
        #pragma unroll
        for (int n = 0; n < 4; ++n) b0[n] = ld_frag(Bb, wn * 64 + n * 16 + flane, 0);
        #pragma unroll
        for (int m = 0; m < 4; ++m) a[m] = ld_frag(Ab, wm * 128 + m * 16 + flane, 0);
        stage_part(H0);                       // A-hi(kt+1), other buffer
        __builtin_amdgcn_s_barrier();
        asm volatile("s_waitcnt lgkmcnt(0)" ::: "memory");
        __builtin_amdgcn_sched_barrier(0);
        __builtin_amdgcn_s_setprio(1);
        #pragma unroll
        for (int m = 0; m < 4; ++m)
            #pragma unroll
            for (int n = 0; n < 4; ++n)
                acc[m][n] = __builtin_amdgcn_mfma_f32_16x16x32_bf16(a[m], b0[n], acc[m][n], 0, 0, 0);
        __builtin_amdgcn_s_setprio(0);
        __builtin_amdgcn_s_barrier();

        // ---- phase 2: kh1, m0-3 (reads b1 + a; B region free afterwards) ----
        #pragma unroll
        for (int n = 0; n < 4; ++n) b1[n] = ld_frag(Bb, wn * 64 + n * 16 + flane, 1);
        #pragma unroll
        for (int m = 0; m < 4; ++m) a[m] = ld_frag(Ab, wm * 128 + m * 16 + flane, 1);
        stage_part(H0 + 1);                   // B-lo(kt+2), issued after B reads
        __builtin_amdgcn_s_barrier();
        asm volatile("s_waitcnt lgkmcnt(0)" ::: "memory");
        __builtin_amdgcn_sched_barrier(0);
        __builtin_amdgcn_s_setprio(1);
        #pragma unroll
        for (int m = 0; m < 4; ++m)
            #pragma unroll
            for (int n = 0; n < 4; ++n)
                acc[m][n] = __builtin_amdgcn_mfma_f32_16x16x32_bf16(a[m], b1[n], acc[m][n], 0, 0, 0);
        __builtin_amdgcn_s_setprio(0);
        __builtin_amdgcn_s_barrier();

        // ---- phase 3: kh0, m4-7 (b0 regs reused) ----
        #pragma unroll
        for (int m = 0; m < 4; ++m) a[m] = ld_frag(Ab, wm * 128 + (m + 4) * 16 + flane, 0);
        stage_part(H0 + 2);                   // B-hi(kt+2), barrier-separated
        __builtin_amdgcn_s_barrier();
        asm volatile("s_waitcnt lgkmcnt(0)" ::: "memory");
        __builtin_amdgcn_sched_barrier(0);
        __builtin_amdgcn_s_setprio(1);
        #pragma unroll
        for (int m = 0; m < 4; ++m)
            #pragma unroll
            for (int n = 0; n < 4; ++n)
                acc[m + 4][n] = __builtin_amdgcn_mfma_f32_16x16x32_bf16(a[m], b0[n], acc[m + 4][n], 0, 0, 0);
        __builtin_amdgcn_s_setprio(0);
        __builtin_amdgcn_s_barrier();

        // ---- phase 4: kh1, m4-7 (b1 regs reused) ----
        #pragma unroll
        for (int m = 0; m < 4; ++m) a[m] = ld_frag(Ab, wm * 128 + (m + 4) * 16 + flane, 1);
        stage_part(H0 + 3);                   // A-lo(kt+2), issued after A reads
        __builtin_amdgcn_s_barrier();
        asm volatile("s_waitcnt lgkmcnt(0)" ::: "memory");
        __builtin_amdgcn_sched_barrier(0);
        __builtin_amdgcn_s_setprio(1);
        #pragma unroll
        for (int m = 0; m < 4; ++m)
            #pragma unroll
            for (int n = 0; n < 4; ++n)
                acc[m + 4][n] = __builtin_amdgcn_mfma_f32_16x16x32_bf16(a[m], b1[n], acc[m + 4][n], 0, 0, 0);
        __builtin_amdgcn_s_setprio(0);
        if (kt < NT - 2) {
            asm volatile("s_waitcnt vmcnt(6)" ::: "memory");   // tile kt+1 fully landed
        } else {
            asm volatile("s_waitcnt vmcnt(0)" ::: "memory");
        }
        __builtin_amdgcn_s_barrier();
    }

    // epilogue: C/D mapping col = lane&15, row = (lane>>4)*4 + j
    const int orow0 = e * TPE + brow * 256 + wm * 128;
    const int ocol0 = bcol * 256 + wn * 64;
    const int rl = (lane >> 4) * 4;
    const int cl = lane & 15;
    #pragma unroll
    for (int m = 0; m < 8; ++m)
        #pragma unroll
        for (int n = 0; n < 4; ++n)
            #pragma unroll
            for (int j = 0; j < 4; ++j) {
                const int r = orow0 + m * 16 + rl + j;
                const int c = ocol0 + n * 16 + cl;
                out[(size_t)r * DOUT_ + c] = acc[m][n][j];
            }
}

extern "C" void kernel_launch(void* const* d_in, const int* in_sizes, int n_in,
                              void* d_out, int out_size, void* d_ws, size_t ws_size,
                              hipStream_t stream) {
    const float* x = (const float*)d_in[0];
    // d_in[1] = tokens_per_expert: reference assumes equal split, unused.
    const float* w = (const float*)d_in[2];
    float* out = (float*)d_out;

    __bf16* xq = (__bf16*)d_ws;
    __bf16* wq = (__bf16*)((char*)d_ws + (size_t)SEQ * DIN_ * sizeof(__bf16));

    quant_x_kernel<<<SEQ / 2, 256, 0, stream>>>(x, xq);
    quant_w_kernel<<<(NE_ * DOUT_ / 128) * (DIN_ / 128), 256, 0, stream>>>(w, wq);
    gemm_kernel<<<NE_ * (TPE / 256) * (DOUT_ / 256), 512, 0, stream>>>(xq, wq, out);
}